// Round 9
// baseline (2037.745 us; speedup 1.0000x reference)
//
#include <hip/hip_runtime.h>
#include <hip/hip_fp16.h>
#include <hip/hip_cooperative_groups.h>

namespace cg = cooperative_groups;

#define NN     65536    // total nodes
#define EE     2097152  // edges
#define HID    32
#define KCH    5
#define OUTS   33
#define NG     8
#define GSZ    262144   // INPUT_SIZE * HIDDEN per graph
#define WLP    40       // padded fp16 row length for Wl (80 B, 16B-aligned)
#define SLICES 64       // edge slices for src histogram
#define RSIZE  32768    // counters per range (2 ranges cover 64K nodes)
#define BSL    16384    // edges per bucketing slice (128 slices)
#define NBK    256      // coarse buckets (dst >> 8)
#define STG    9472     // LDS staging capacity in k_place
#define NPART  8        // src partitions per dst edge list (8192-node ranges)
#define EPCAP  (EE + 7 * NN)   // padded edge list capacity
#define DBIN   256      // degree-sort bins (len8 fits in 8 bits)

typedef _Float16 half8 __attribute__((ext_vector_type(8)));
typedef float floatx4 __attribute__((ext_vector_type(4)));

// exclusive scan of sh[0..255] in place; whole block must call
__device__ __forceinline__ void exscan256(int tid, int* __restrict__ sh,
                                          int* __restrict__ wsc) {
    int v = 0, s = 0;
    if (tid < 256) {
        v = sh[tid];
        s = v;
        int lane = tid & 63;
        #pragma unroll
        for (int off = 1; off < 64; off <<= 1) {
            int t = __shfl_up(s, off, 64);
            if (lane >= off) s += t;
        }
        if (lane == 63) wsc[tid >> 6] = s;
    }
    __syncthreads();
    if (tid == 0) {
        int a = 0;
        #pragma unroll
        for (int i = 0; i < 4; ++i) { int t = wsc[i]; wsc[i] = a; a += t; }
    }
    __syncthreads();
    if (tid < 256) sh[tid] = s - v + wsc[tid >> 6];
    __syncthreads();
}

// ------- fused: src out-degree histogram (blocks 0..127) + dst bucket counts
__global__ __launch_bounds__(1024) void k_hist2(const int* __restrict__ ei,
                                                unsigned char* __restrict__ pdeg,
                                                int* __restrict__ bcnt) {
    __shared__ unsigned cnt[RSIZE];
    int b = blockIdx.x, tid = threadIdx.x;
    if (b < 128) {
        int r = (b >> 6) & 1, s = b & 63;
        const int* keys = ei + s * (EE / SLICES);
        unsigned char* pout = pdeg + (size_t)(r * SLICES + s) * RSIZE;
        for (int i = tid; i < RSIZE; i += 1024) cnt[i] = 0;
        __syncthreads();
        int lo = r * RSIZE, hi = lo + RSIZE;
        for (int i = tid; i < EE / SLICES; i += 1024) {
            int k = keys[i];
            if (k >= lo && k < hi) atomicAdd(&cnt[k - lo], 1u);
        }
        __syncthreads();
        unsigned* pout4 = (unsigned*)pout;
        for (int i = tid; i < RSIZE / 4; i += 1024) {
            unsigned c0 = cnt[4 * i], c1 = cnt[4 * i + 1];
            unsigned c2 = cnt[4 * i + 2], c3 = cnt[4 * i + 3];
            pout4[i] = c0 | (c1 << 8) | (c2 << 16) | (c3 << 24);
        }
    } else {
        int s = b - 128;
        if (tid < NBK) cnt[tid] = 0;
        __syncthreads();
        const int* dsts = ei + EE + s * BSL;
        for (int i = tid; i < BSL; i += 1024)
            atomicAdd(&cnt[dsts[i] >> 8], 1u);
        __syncthreads();
        if (tid < NBK) bcnt[s * NBK + tid] = (int)cnt[tid];
    }
}

// ------- fused: partial-hist reduce -> dinv, sdeg, u0 = fp16(dinv*x)
//         (blocks 0..63) + bucket scan ------------------------------------
__global__ __launch_bounds__(256) void k_hredscan(const unsigned char* __restrict__ pdeg,
                                                  float* __restrict__ dinv,
                                                  float* __restrict__ sdeg,
                                                  int* __restrict__ bcnt,
                                                  int* __restrict__ bbase,
                                                  const float* __restrict__ x,
                                                  __half* __restrict__ ub0) {
    int blk = blockIdx.x, tid = threadIdx.x;
    if (blk < 64) {
        int t = blk * 256 + tid;
        int r = t >> 13, ql = t & 8191;
        const unsigned* base = (const unsigned*)(pdeg + (size_t)r * SLICES * RSIZE) + ql;
        unsigned s0 = 0, s1 = 0, s2 = 0, s3 = 0;
#pragma unroll 8
        for (int s = 0; s < SLICES; ++s) {
            unsigned v = base[s * (RSIZE / 4)];
            s0 += v & 0xFF; s1 += (v >> 8) & 0xFF; s2 += (v >> 16) & 0xFF; s3 += v >> 24;
        }
        int c = (r << 15) + 4 * ql;
        float d0 = s0 ? 1.0f / sqrtf((float)s0) : 0.0f;
        float d1 = s1 ? 1.0f / sqrtf((float)s1) : 0.0f;
        float d2 = s2 ? 1.0f / sqrtf((float)s2) : 0.0f;
        float d3 = s3 ? 1.0f / sqrtf((float)s3) : 0.0f;
        dinv[c] = d0; dinv[c + 1] = d1; dinv[c + 2] = d2; dinv[c + 3] = d3;
        sdeg[c]     = s0 ? sqrtf((float)s0) : 0.0f;
        sdeg[c + 1] = s1 ? sqrtf((float)s1) : 0.0f;
        sdeg[c + 2] = s2 ? sqrtf((float)s2) : 0.0f;
        sdeg[c + 3] = s3 ? sqrtf((float)s3) : 0.0f;
        ub0[c]     = __float2half(d0 * x[c]);
        ub0[c + 1] = __float2half(d1 * x[c + 1]);
        ub0[c + 2] = __float2half(d2 * x[c + 2]);
        ub0[c + 3] = __float2half(d3 * x[c + 3]);
    } else {
        __shared__ int tot[256];
        __shared__ int wsc[4];
        int b = tid;
        int run = 0;
        for (int s = 0; s < 128; ++s) {
            int c = bcnt[s * NBK + b];
            bcnt[s * NBK + b] = run;
            run += c;
        }
        tot[b] = run;
        __syncthreads();
        exscan256(b, tot, wsc);
        bbase[b] = tot[b];
        if (b == 0) bbase[256] = EE;
        for (int s = 0; s < 128; ++s)
            bcnt[s * NBK + b] += tot[b];
    }
}

// ---------------- coarse bucketing: LDS counting sort, coalesced flush ------
__global__ __launch_bounds__(1024) void k_bucket(const int* __restrict__ ei,
                                                 const int* __restrict__ boff,
                                                 unsigned* __restrict__ bkt) {
    __shared__ unsigned stage[BSL];
    __shared__ int cnt[NBK], cur[NBK], gbase[NBK];
    __shared__ int wsc[4];
    int s = blockIdx.x, tid = threadIdx.x;
    if (tid < NBK) cnt[tid] = 0;
    __syncthreads();
    const int* srcs = ei + s * BSL;
    const int* dsts = ei + EE + s * BSL;
    for (int i = tid; i < BSL; i += 1024)
        atomicAdd(&cnt[dsts[i] >> 8], 1);
    __syncthreads();
    if (tid < NBK) gbase[tid] = boff[s * NBK + tid];
    exscan256(tid, cnt, wsc);
    if (tid < NBK) cur[tid] = cnt[tid];
    __syncthreads();
    for (int i = tid; i < BSL; i += 1024) {
        int d = dsts[i];
        int pos = atomicAdd(&cur[d >> 8], 1);
        stage[pos] = (unsigned)srcs[i] | ((unsigned)d << 16);
    }
    __syncthreads();
    for (int j = tid; j < BSL; j += 1024) {
        unsigned rec = stage[j];
        int b = rec >> 24;
        bkt[gbase[b] + (j - cnt[b])] = rec;
    }
}

// -------- fine placement: exact CSR (rowp), src-only records; per-dst edge
//          lists ordered in 8 src-range runs (partitions 0-3 = src<32768) ---
__global__ __launch_bounds__(512) void k_place(const unsigned* __restrict__ bkt,
                                               const int* __restrict__ bbase,
                                               unsigned* __restrict__ ep,
                                               int* __restrict__ rowp) {
    __shared__ unsigned stage[STG];
    __shared__ int histP[NPART][NBK], curP[NPART][NBK];
    __shared__ int tot[NBK];
    __shared__ int wsc[4];
    int b = blockIdx.x, tid = threadIdx.x;
    int base = bbase[b], cnt = bbase[b + 1] - base;
    if (tid < NBK) {
#pragma unroll
        for (int p = 0; p < NPART; ++p) histP[p][tid] = 0;
    }
    __syncthreads();
    const unsigned* recs = bkt + base;
    for (int i = tid; i < cnt; i += 512) {
        unsigned rec = recs[i];
        atomicAdd(&histP[(rec & 0xFFFFu) >> 13][(rec >> 16) & 255], 1);
    }
    __syncthreads();
    if (tid < NBK) {
        int s = 0;
#pragma unroll
        for (int p = 0; p < NPART; ++p) s += histP[p][tid];
        tot[tid] = s;
    }
    __syncthreads();
    exscan256(tid, tot, wsc);                   // tot = exclusive start per dlow
    if (tid < NBK) {
        int st = tot[tid];
        rowp[b * NBK + tid] = base + st;
#pragma unroll
        for (int p = 0; p < NPART; ++p) {
            curP[p][tid] = st;
            st += histP[p][tid];
        }
    }
    if (b == 0 && tid == 0) rowp[NN] = EE;
    __syncthreads();
    for (int i = tid; i < cnt; i += 512) {
        unsigned rec = recs[i];
        int srcv = rec & 0xFFFF;
        int dlow = (rec >> 16) & 255;
        int pos = atomicAdd(&curP[srcv >> 13][dlow], 1);
        unsigned pk = (unsigned)srcv;
        if (pos < STG) stage[pos] = pk; else ep[base + pos] = pk;
    }
    __syncthreads();
    int lim = cnt < STG ? cnt : STG;
    for (int j = tid; j < lim; j += 512)
        ep[base + j] = stage[j];
}

// -------- degree-sort pass 1: per-block len8 histogram ---------------------
__global__ __launch_bounds__(1024) void k_dhist(const int* __restrict__ rowp,
                                                int* __restrict__ bh) {
    __shared__ int hist[DBIN];
    int blk = blockIdx.x, tid = threadIdx.x;
    if (tid < DBIN) hist[tid] = 0;
    __syncthreads();
    int n = blk * 1024 + tid;
    int deg = rowp[n + 1] - rowp[n];
    int pd = (deg + 7) & ~7;
    atomicAdd(&hist[pd >> 3], 1);
    __syncthreads();
    if (tid < DBIN) bh[blk * DBIN + tid] = hist[tid];
}

// -------- degree-sort pass 2: bin node-starts, bin edge-starts (closed-form
//          since all rows in bin have pd = 8*bin), per-block offsets --------
__global__ __launch_bounds__(256) void k_doff(const int* __restrict__ bh,
                                              int* __restrict__ off,
                                              int* __restrict__ nstart,
                                              int* __restrict__ estart) {
    __shared__ int tot[256];
    __shared__ int tote[256];
    __shared__ int wsc[4];
    int bin = threadIdx.x;
    int run = 0;
    for (int b = 0; b < 64; ++b) run += bh[b * DBIN + bin];
    tot[bin] = run;
    tote[bin] = run * (bin << 3);
    __syncthreads();
    exscan256(bin, tot, wsc);                    // node start per bin
    exscan256(bin, tote, wsc);                   // edge start per bin
    nstart[bin] = tot[bin];
    estart[bin] = tote[bin];
    int st = tot[bin];
    for (int b = 0; b < 64; ++b) {
        off[b * DBIN + bin] = st;
        st += bh[b * DBIN + bin];
    }
}

// -------- degree-sort pass 3: emit desc2 in sorted order with closed-form
//          padded edge offsets; rowp2[n] = sorted e0 -----------------------
__global__ __launch_bounds__(1024) void k_dscat(const int* __restrict__ rowp,
                                                const int* __restrict__ off,
                                                const int* __restrict__ nstart,
                                                const int* __restrict__ estart,
                                                uint4* __restrict__ desc2,
                                                int* __restrict__ rowp2) {
    __shared__ int loff[DBIN];
    int blk = blockIdx.x, tid = threadIdx.x;
    if (tid < DBIN) loff[tid] = off[blk * DBIN + tid];
    __syncthreads();
    int n = blk * 1024 + tid;
    int deg = rowp[n + 1] - rowp[n];
    int pd = (deg + 7) & ~7;
    int bin = pd >> 3;
    int pos = atomicAdd(&loff[bin], 1);
    int e0 = estart[bin] + (pos - nstart[bin]) * pd;
    desc2[pos] = make_uint4((unsigned)e0,
                            (unsigned)n | ((unsigned)bin << 16) |
                                ((unsigned)(pd - deg) << 24),
                            0u, 0u);
    rowp2[n] = e0;
}

// -------- emit padded ushort edge list AT SORTED OFFSETS (pads = 0xFFFF ->
//          row 65535, compensated by count) --------------------------------
__global__ __launch_bounds__(256) void k_copy(const int* __restrict__ rowp,
                                              const int* __restrict__ rowp2,
                                              const unsigned* __restrict__ ep,
                                              unsigned short* __restrict__ epp) {
    int idx = blockIdx.x * 256 + threadIdx.x;
    int n = idx >> 2, l = idx & 3;
    int a0 = rowp[n], a1 = rowp[n + 1], deg = a1 - a0;
    int b0 = rowp2[n];
    int pd = (deg + 7) & ~7;
    for (int i = l; i < deg; i += 4)
        epp[b0 + i] = (unsigned short)(ep[a0 + i] & 0xFFFFu);
    for (int i = deg + l; i < pd; i += 4) epp[b0 + i] = (unsigned short)0xFFFFu;
}

// ------- fused converts: Wl->fp16 padded-40 (blocks 0..2047), W2/W3 -> fp16
//         transposed (2048..2087), out bias init (2088) --------------------
__global__ __launch_bounds__(256) void k_cvtall(const float* __restrict__ Wl,
                                                __half* __restrict__ Wlh,
                                                const float* __restrict__ W2,
                                                const float* __restrict__ W3,
                                                _Float16* __restrict__ Wt2,
                                                _Float16* __restrict__ Wt3,
                                                const float* __restrict__ bl,
                                                float* __restrict__ out) {
    int blk = blockIdx.x, tid = threadIdx.x;
    if (blk < 2048) {
        __shared__ float s[128 * 33];
        const float* src = Wl + (size_t)blk * 128 * 33;
        for (int t = tid; t < 128 * 33; t += 256) s[t] = src[t];
        __syncthreads();
        unsigned* dst = (unsigned*)(Wlh + (size_t)blk * 128 * WLP);
        for (int t = tid; t < 128 * (WLP / 2); t += 256) {
            int row = t / (WLP / 2), c2 = t - row * (WLP / 2);
            int c0 = 2 * c2;
            float f0 = (c0 < 33) ? s[row * 33 + c0] : 0.f;
            float f1 = (c0 + 1 < 33) ? s[row * 33 + c0 + 1] : 0.f;
            __half2 h = __floats2half2_rn(f0, f1);
            dst[t] = *(unsigned*)&h;
        }
    } else if (blk < 2088) {
        int t = (blk - 2048) * 256 + tid;     // 0..10239
        const float* W = (t < 5120) ? W2 : W3;
        _Float16* Wt   = (t < 5120) ? Wt2 : Wt3;
        int tt = (t < 5120) ? t : t - 5120;
        if (tt < KCH * HID * HID) {
            int kc = tt >> 10, rem = tt & 1023, j = rem >> 5, i = rem & 31;
            Wt[tt] = (_Float16)W[kc * 1024 + i * 32 + j];
        }
    } else {
        if (tid < NG * OUTS) out[tid] = bl[tid % OUTS];
    }
}

// =================== fused network (cooperative) ===========================
// grid 256 x 1024 threads (= NN*4 lanes), 128 KB LDS, 1 block/CU.
// phases separated by grid.sync(); each phase is the verified standalone
// kernel's body with identical indexing.

// width-1 fp16 u-space prop, single 128 KB LDS stage of the whole table
__device__ __forceinline__ void prop1_phase(int tid, int blk,
        const uint4* __restrict__ desc, const unsigned short* __restrict__ epp,
        const __half* __restrict__ uin, const __half* __restrict__ uprev,
        const float* __restrict__ dinv, __half* __restrict__ uout,
        float alpha, _Float16* __restrict__ lds) {
    int q = blk * 256 + (tid >> 2), l = tid & 3;
    uint4 d = desc[q];
    int e0 = (int)d.x;
    int n = d.y & 0xFFFF;
    int len8 = (d.y >> 16) & 0xFF;
    int pads = (int)(d.y >> 24);
    int e1 = e0 + (len8 << 3);
    {
        float4* l4 = (float4*)lds;
        const float4* u4 = (const float4*)uin;
        for (int i = tid; i < 8192; i += 1024) l4[i] = u4[i];
    }
    __syncthreads();
    float a = 0.f;
    for (int e = e0 + l; e < e1; e += 4) a += (float)lds[epp[e]];
    a += __shfl_xor(a, 1, 64);
    a += __shfl_xor(a, 2, 64);
    if (l == 0) {
        a -= (float)pads * (float)lds[65535];
        float dn = dinv[n];
        float u = -alpha * dn * dn * a;
        if (uprev) u -= __half2float(uprev[n]);
        uout[n] = __float2half(u);
    }
}

// width-32 fp16 u-space prop: 4 lanes/node, padded uniform 8-edge loop
__device__ __forceinline__ void prop32_phase(int tid, int blk,
        const uint4* __restrict__ desc, const unsigned short* __restrict__ epp,
        const __half* __restrict__ uin, const __half* __restrict__ uprev,
        const float* __restrict__ dinv, __half* __restrict__ uout,
        float alpha) {
    int idx = blk * 1024 + tid;
    int q = idx >> 2, j8 = (idx & 3) << 3;
    uint4 d = desc[q];
    int e0 = (int)d.x;
    int n = d.y & 0xFFFF;
    int len8 = (d.y >> 16) & 0xFF;
    int pads = (int)(d.y >> 24);
    int e1 = e0 + (len8 << 3);
    const _Float16* tf = (const _Float16*)uin;
    float acc[8];
#pragma unroll
    for (int i = 0; i < 8; ++i) acc[i] = 0.f;
    for (int e = e0; e < e1; e += 8) {
        uint4 pk = *(const uint4*)(epp + e);
        unsigned s0 = pk.x & 0xFFFFu, s1 = pk.x >> 16;
        unsigned s2 = pk.y & 0xFFFFu, s3 = pk.y >> 16;
        unsigned s4 = pk.z & 0xFFFFu, s5 = pk.z >> 16;
        unsigned s6 = pk.w & 0xFFFFu, s7 = pk.w >> 16;
        half8 v0 = *(const half8*)(tf + (s0 << 5) + j8);
        half8 v1 = *(const half8*)(tf + (s1 << 5) + j8);
        half8 v2 = *(const half8*)(tf + (s2 << 5) + j8);
        half8 v3 = *(const half8*)(tf + (s3 << 5) + j8);
        half8 v4 = *(const half8*)(tf + (s4 << 5) + j8);
        half8 v5 = *(const half8*)(tf + (s5 << 5) + j8);
        half8 v6 = *(const half8*)(tf + (s6 << 5) + j8);
        half8 v7 = *(const half8*)(tf + (s7 << 5) + j8);
#pragma unroll
        for (int i = 0; i < 8; ++i)
            acc[i] += (float)v0[i] + (float)v1[i] + (float)v2[i] + (float)v3[i]
                    + (float)v4[i] + (float)v5[i] + (float)v6[i] + (float)v7[i];
    }
    if (pads) {
        half8 z = *(const half8*)(tf + (0xFFFFu << 5) + j8);
        float pf = (float)pads;
#pragma unroll
        for (int i = 0; i < 8; ++i) acc[i] -= pf * (float)z[i];
    }
    float dn = dinv[n];
    float coef = -alpha * dn * dn;
    int o = (n << 5) + j8;
    half8 hu;
    if (uprev) {
        half8 pv = *(const half8*)((const _Float16*)uprev + o);
#pragma unroll
        for (int i = 0; i < 8; ++i) hu[i] = (_Float16)(coef * acc[i] - (float)pv[i]);
    } else {
#pragma unroll
        for (int i = 0; i < 8; ++i) hu[i] = (_Float16)(coef * acc[i]);
    }
    *(half8*)((_Float16*)uout + o) = hu;
}

// layer-1 combine (grid-stride over NN*HID)
__device__ __forceinline__ void comb1_phase(int tid, int blk,
        const float* __restrict__ x, const __half* __restrict__ ub,
        const float* __restrict__ W, const float* __restrict__ b,
        const float* __restrict__ sdeg, const float* __restrict__ dinv,
        __half* __restrict__ uout) {
    for (int idx = blk * 1024 + tid; idx < NN * HID; idx += 256 * 1024) {
        int n = idx >> 5, j = idx & 31;
        float uacc = 0.f;
#pragma unroll
        for (int k = 1; k < KCH; ++k)
            uacc += __half2float(ub[k * NN + n]) * W[k * HID + j];
        float h = fmaxf(b[j] + x[n] * W[j] + sdeg[n] * uacc, 0.f);
        uout[idx] = __float2half(dinv[n] * h);
    }
}

// MFMA combine: 4096 waves, one 16-row tile each
__device__ __forceinline__ void comb32_phase(int tid, int blk,
        const __half* tx, const _Float16* __restrict__ Wt,
        const float* __restrict__ b, const float* __restrict__ sdeg,
        const float* __restrict__ dinv, __half* hout, __half* uout, int relu) {
    int lane = tid & 63;
    int wave = (blk * 1024 + tid) >> 6;       // 0..4095
    int m = lane & 15, kg = lane >> 4;
    half8 Bf[KCH][2];
#pragma unroll
    for (int kc = 0; kc < KCH; ++kc)
#pragma unroll
        for (int h = 0; h < 2; ++h)
            Bf[kc][h] = *(const half8*)(Wt + kc * 1024 + (h * 16 + m) * 32 + kg * 8);
    float bj0 = b[m], bj1 = b[16 + m];
    const size_t S = (size_t)NN * HID;
    const _Float16* txf = (const _Float16*)tx;
    int nb = wave << 4;
    floatx4 acc0 = {0.f, 0.f, 0.f, 0.f}, acc1 = {0.f, 0.f, 0.f, 0.f};
#pragma unroll
    for (int kc = 0; kc < KCH; ++kc) {
        half8 Af = *(const half8*)(txf + (size_t)kc * S + (size_t)(nb + m) * 32 + kg * 8);
        acc0 = __builtin_amdgcn_mfma_f32_16x16x32_f16(Af, Bf[kc][0], acc0, 0, 0, 0);
        acc1 = __builtin_amdgcn_mfma_f32_16x16x32_f16(Af, Bf[kc][1], acc1, 0, 0, 0);
    }
    int rowb = nb + kg * 4;
#pragma unroll
    for (int r = 0; r < 4; ++r) {
        int row = rowb + r;
        float sd = sdeg[row];
        float v0 = sd * acc0[r] + bj0, v1 = sd * acc1[r] + bj1;
        if (relu) { v0 = fmaxf(v0, 0.f); v1 = fmaxf(v1, 0.f); }
        if (hout) {
            hout[(size_t)row * 32 + m]      = __float2half(v0);
            hout[(size_t)row * 32 + 16 + m] = __float2half(v1);
        }
        if (uout) {
            float dn = dinv[row];
            uout[(size_t)row * 32 + m]      = __float2half(dn * v0);
            uout[(size_t)row * 32 + 16 + m] = __float2half(dn * v1);
        }
    }
}

__global__ __launch_bounds__(1024) void k_net(
        const uint4* __restrict__ desc, const unsigned short* __restrict__ epp,
        __half* __restrict__ ub, const float* __restrict__ dinv,
        const float* __restrict__ sdeg, const float* __restrict__ x,
        const float* __restrict__ W1, const float* __restrict__ b1,
        __half* __restrict__ utx, const _Float16* __restrict__ Wt2,
        const float* __restrict__ b2, const _Float16* __restrict__ Wt3,
        const float* __restrict__ b3, __half* __restrict__ hfin) {
    __shared__ _Float16 lds[65536];            // 128 KB (prop1 phases only)
    cg::grid_group grid = cg::this_grid();
    int tid = threadIdx.x, blk = blockIdx.x;
    const size_t S = (size_t)NN * HID;

    // ---- layer 1 ----
    prop1_phase(tid, blk, desc, epp, ub,          nullptr,     dinv, ub + NN,     1.f, lds);
    __threadfence(); grid.sync();
    prop1_phase(tid, blk, desc, epp, ub + NN,     ub,          dinv, ub + 2 * NN, 2.f, lds);
    __threadfence(); grid.sync();
    prop1_phase(tid, blk, desc, epp, ub + 2 * NN, ub + NN,     dinv, ub + 3 * NN, 2.f, lds);
    __threadfence(); grid.sync();
    prop1_phase(tid, blk, desc, epp, ub + 3 * NN, ub + 2 * NN, dinv, ub + 4 * NN, 2.f, lds);
    __threadfence(); grid.sync();
    comb1_phase(tid, blk, x, ub, W1, b1, sdeg, dinv, utx);
    __threadfence(); grid.sync();

    // ---- layer 2 ----
    prop32_phase(tid, blk, desc, epp, utx,         nullptr,      dinv, utx + 1 * S, 1.f);
    __threadfence(); grid.sync();
    prop32_phase(tid, blk, desc, epp, utx + 1 * S, utx,          dinv, utx + 2 * S, 2.f);
    __threadfence(); grid.sync();
    prop32_phase(tid, blk, desc, epp, utx + 2 * S, utx + 1 * S,  dinv, utx + 3 * S, 2.f);
    __threadfence(); grid.sync();
    prop32_phase(tid, blk, desc, epp, utx + 3 * S, utx + 2 * S,  dinv, utx + 4 * S, 2.f);
    __threadfence(); grid.sync();
    comb32_phase(tid, blk, utx, Wt2, b2, sdeg, dinv, nullptr, utx, 1);
    __threadfence(); grid.sync();

    // ---- layer 3 ----
    prop32_phase(tid, blk, desc, epp, utx,         nullptr,      dinv, utx + 1 * S, 1.f);
    __threadfence(); grid.sync();
    prop32_phase(tid, blk, desc, epp, utx + 1 * S, utx,          dinv, utx + 2 * S, 2.f);
    __threadfence(); grid.sync();
    prop32_phase(tid, blk, desc, epp, utx + 2 * S, utx + 1 * S,  dinv, utx + 3 * S, 2.f);
    __threadfence(); grid.sync();
    prop32_phase(tid, blk, desc, epp, utx + 3 * S, utx + 2 * S,  dinv, utx + 4 * S, 2.f);
    __threadfence(); grid.sync();
    comb32_phase(tid, blk, utx, Wt3, b3, sdeg, nullptr, hfin, nullptr, 0);
}

// ---------------- readout: 5x dwordx4 Wl rows ----------------
__global__ __launch_bounds__(256) void k_readout(const __half* __restrict__ h,
                                                 const __half* __restrict__ Wlh,
                                                 float* __restrict__ out) {
    int gp = blockIdx.x >> 7;
    int mc = blockIdx.x & 127;
    int tid = threadIdx.x;
    int g0 = gp * 2, g1 = g0 + 1;
    float acc0[OUTS], acc1[OUTS];
#pragma unroll
    for (int o = 0; o < OUTS; ++o) { acc0[o] = 0.f; acc1[o] = 0.f; }
    const __half* h0 = h + (size_t)g0 * GSZ;
    const __half* h1 = h + (size_t)g1 * GSZ;
    for (int it = 0; it < 8; ++it) {
        int m = mc * 2048 + it * 256 + tid;
        float hv0 = __half2float(h0[m]);
        float hv1 = __half2float(h1[m]);
        const uint4* rp = (const uint4*)(Wlh + (size_t)m * WLP);   // 80B rows, 16B aligned
        uint4 q0 = rp[0], q1 = rp[1], q2 = rp[2], q3 = rp[3], q4 = rp[4];
        unsigned u[17] = {q0.x, q0.y, q0.z, q0.w, q1.x, q1.y, q1.z, q1.w,
                          q2.x, q2.y, q2.z, q2.w, q3.x, q3.y, q3.z, q3.w, q4.x};
#pragma unroll
        for (int q = 0; q < 16; ++q) {
            float2 f = __half22float2(*(__half2*)&u[q]);
            acc0[2 * q]     += hv0 * f.x;  acc1[2 * q]     += hv1 * f.x;
            acc0[2 * q + 1] += hv0 * f.y;  acc1[2 * q + 1] += hv1 * f.y;
        }
        float lw = __half2float(__low2half(*(__half2*)&u[16]));
        acc0[32] += hv0 * lw;  acc1[32] += hv1 * lw;
    }
    __shared__ float red[4][2 * OUTS];
    int lane = tid & 63, w = tid >> 6;
#pragma unroll
    for (int o = 0; o < OUTS; ++o) {
        float v0 = acc0[o], v1 = acc1[o];
        for (int off = 32; off > 0; off >>= 1) {
            v0 += __shfl_down(v0, off, 64);
            v1 += __shfl_down(v1, off, 64);
        }
        if (lane == 0) { red[w][o] = v0; red[w][OUTS + o] = v1; }
    }
    __syncthreads();
    if (tid < 2 * OUTS) {
        float s = red[0][tid] + red[1][tid] + red[2][tid] + red[3][tid];
        int g = (tid < OUTS) ? g0 : g1;
        int o = (tid < OUTS) ? tid : tid - OUTS;
        atomicAdd(&out[g * OUTS + o], s);
    }
}

extern "C" void kernel_launch(void* const* d_in, const int* in_sizes, int n_in,
                              void* d_out, int out_size, void* d_ws, size_t ws_size,
                              hipStream_t stream) {
    const float* x  = (const float*)d_in[0];
    const int*   ei = (const int*)d_in[1];
    const float* W1 = (const float*)d_in[3];
    const float* b1 = (const float*)d_in[4];
    const float* W2 = (const float*)d_in[5];
    const float* b2 = (const float*)d_in[6];
    const float* W3 = (const float*)d_in[7];
    const float* b3 = (const float*)d_in[8];
    const float* Wl = (const float*)d_in[9];
    const float* bl = (const float*)d_in[10];
    float* out = (float*)d_out;

    char* ws = (char*)d_ws;
    size_t off = 0;
    auto alloc = [&](size_t bytes) -> void* {
        void* p = ws + off;
        off += (bytes + 255) & ~(size_t)255;
        return p;
    };
    unsigned char* pdeg = (unsigned char*)alloc((size_t)2 * SLICES * RSIZE);
    int*      bcnt   = (int*)alloc((size_t)128 * NBK * 4);
    int*      bbase  = (int*)alloc((size_t)257 * 4);
    int*      rowp   = (int*)alloc((size_t)(NN + 1) * 4);
    int*      rowp2  = (int*)alloc((size_t)NN * 4);
    int*      bh     = (int*)alloc((size_t)64 * DBIN * 4);
    int*      boffs  = (int*)alloc((size_t)64 * DBIN * 4);
    int*      nstart = (int*)alloc((size_t)DBIN * 4);
    int*      estart = (int*)alloc((size_t)DBIN * 4);
    float*    dinv   = (float*)alloc((size_t)NN * 4);
    float*    sdeg   = (float*)alloc((size_t)NN * 4);
    unsigned* bkt    = (unsigned*)alloc((size_t)EE * 4);
    unsigned* ep     = (unsigned*)alloc((size_t)EE * 4);
    unsigned short* epp = (unsigned short*)alloc((size_t)EPCAP * 2);
    uint4*    desc2  = (uint4*)alloc((size_t)NN * 16);
    __half*   ub     = (__half*)alloc((size_t)5 * NN * 2);          // u0..u4 (layer 1, fp16)
    __half*   utx    = (__half*)alloc((size_t)KCH * NN * HID * 2);  // u0..u4 (layers 2/3)
    __half*   hfin   = (__half*)alloc((size_t)NN * HID * 2);
    __half*   Wlh    = (__half*)alloc((size_t)GSZ * WLP * 2);
    _Float16* Wt2    = (_Float16*)alloc((size_t)KCH * HID * HID * 2);
    _Float16* Wt3    = (_Float16*)alloc((size_t)KCH * HID * HID * 2);

    // ---- CSR build (atomic-free) + degree-sorted padded edge list ----
    k_hist2<<<256, 1024, 0, stream>>>(ei, pdeg, bcnt);
    k_hredscan<<<65, 256, 0, stream>>>(pdeg, dinv, sdeg, bcnt, bbase, x, ub);
    k_bucket<<<128, 1024, 0, stream>>>(ei, bcnt, bkt);
    k_place<<<256, 512, 0, stream>>>(bkt, bbase, ep, rowp);
    k_dhist<<<64, 1024, 0, stream>>>(rowp, bh);
    k_doff<<<1, 256, 0, stream>>>(bh, boffs, nstart, estart);
    k_dscat<<<64, 1024, 0, stream>>>(rowp, boffs, nstart, estart, desc2, rowp2);
    k_copy<<<1024, 256, 0, stream>>>(rowp, rowp2, ep, epp);
    k_cvtall<<<2089, 256, 0, stream>>>(Wl, Wlh, W2, W3, Wt2, Wt3, bl, out);

    // ---- fused 3-layer network (cooperative, 15 phases / 14 grid syncs) ----
    {
        const uint4* descA = desc2;
        const unsigned short* eppA = epp;
        void* args[] = {
            (void*)&descA, (void*)&eppA, (void*)&ub, (void*)&dinv,
            (void*)&sdeg, (void*)&x, (void*)&W1, (void*)&b1,
            (void*)&utx, (void*)&Wt2, (void*)&b2, (void*)&Wt3,
            (void*)&b3, (void*)&hfin
        };
        hipLaunchCooperativeKernel((void*)k_net, dim3(256), dim3(1024),
                                   args, 0, stream);
    }

    // ---- readout ----
    k_readout<<<512, 256, 0, stream>>>(hfin, Wlh, out);
}

// Round 10
// 385.439 us; speedup vs baseline: 5.2868x; 5.2868x over previous
//
#include <hip/hip_runtime.h>
#include <hip/hip_fp16.h>

#define NN     65536    // total nodes
#define EE     2097152  // edges
#define HID    32
#define KCH    5
#define OUTS   33
#define NG     8
#define GSZ    262144   // INPUT_SIZE * HIDDEN per graph
#define WLP    40       // padded fp16 row length for Wl (80 B, 16B-aligned)
#define SLICES 64       // edge slices for src histogram
#define RSIZE  32768    // counters per range (2 ranges cover 64K nodes)
#define BSL    16384    // edges per bucketing slice (128 slices)
#define NBK    256      // coarse buckets (dst >> 8)
#define STG    9472     // LDS staging capacity in k_place
#define NPART  8        // src partitions per dst edge list (8192-node ranges)
#define EPCAP  (EE + 7 * NN)   // padded edge list capacity
#define DBIN   256      // degree-sort bins (len8 fits in 8 bits)

typedef _Float16 half8 __attribute__((ext_vector_type(8)));
typedef float floatx4 __attribute__((ext_vector_type(4)));

// exclusive scan of sh[0..255] in place; whole block must call
__device__ __forceinline__ void exscan256(int tid, int* __restrict__ sh,
                                          int* __restrict__ wsc) {
    int v = 0, s = 0;
    if (tid < 256) {
        v = sh[tid];
        s = v;
        int lane = tid & 63;
        #pragma unroll
        for (int off = 1; off < 64; off <<= 1) {
            int t = __shfl_up(s, off, 64);
            if (lane >= off) s += t;
        }
        if (lane == 63) wsc[tid >> 6] = s;
    }
    __syncthreads();
    if (tid == 0) {
        int a = 0;
        #pragma unroll
        for (int i = 0; i < 4; ++i) { int t = wsc[i]; wsc[i] = a; a += t; }
    }
    __syncthreads();
    if (tid < 256) sh[tid] = s - v + wsc[tid >> 6];
    __syncthreads();
}

// ------- fused: src out-degree histogram (blocks 0..127) + dst bucket counts
__global__ __launch_bounds__(1024) void k_hist2(const int* __restrict__ ei,
                                                unsigned char* __restrict__ pdeg,
                                                int* __restrict__ bcnt) {
    __shared__ unsigned cnt[RSIZE];
    int b = blockIdx.x, tid = threadIdx.x;
    if (b < 128) {
        int r = (b >> 6) & 1, s = b & 63;
        const int* keys = ei + s * (EE / SLICES);
        unsigned char* pout = pdeg + (size_t)(r * SLICES + s) * RSIZE;
        for (int i = tid; i < RSIZE; i += 1024) cnt[i] = 0;
        __syncthreads();
        int lo = r * RSIZE, hi = lo + RSIZE;
        for (int i = tid; i < EE / SLICES; i += 1024) {
            int k = keys[i];
            if (k >= lo && k < hi) atomicAdd(&cnt[k - lo], 1u);
        }
        __syncthreads();
        unsigned* pout4 = (unsigned*)pout;
        for (int i = tid; i < RSIZE / 4; i += 1024) {
            unsigned c0 = cnt[4 * i], c1 = cnt[4 * i + 1];
            unsigned c2 = cnt[4 * i + 2], c3 = cnt[4 * i + 3];
            pout4[i] = c0 | (c1 << 8) | (c2 << 16) | (c3 << 24);
        }
    } else {
        int s = b - 128;
        if (tid < NBK) cnt[tid] = 0;
        __syncthreads();
        const int* dsts = ei + EE + s * BSL;
        for (int i = tid; i < BSL; i += 1024)
            atomicAdd(&cnt[dsts[i] >> 8], 1u);
        __syncthreads();
        if (tid < NBK) bcnt[s * NBK + tid] = (int)cnt[tid];
    }
}

// ------- fused: partial-hist reduce -> dinv, sdeg, u0 = fp16(dinv*x)
//         (blocks 0..63) + bucket scan ------------------------------------
__global__ __launch_bounds__(256) void k_hredscan(const unsigned char* __restrict__ pdeg,
                                                  float* __restrict__ dinv,
                                                  float* __restrict__ sdeg,
                                                  int* __restrict__ bcnt,
                                                  int* __restrict__ bbase,
                                                  const float* __restrict__ x,
                                                  __half* __restrict__ ub0) {
    int blk = blockIdx.x, tid = threadIdx.x;
    if (blk < 64) {
        int t = blk * 256 + tid;
        int r = t >> 13, ql = t & 8191;
        const unsigned* base = (const unsigned*)(pdeg + (size_t)r * SLICES * RSIZE) + ql;
        unsigned s0 = 0, s1 = 0, s2 = 0, s3 = 0;
#pragma unroll 8
        for (int s = 0; s < SLICES; ++s) {
            unsigned v = base[s * (RSIZE / 4)];
            s0 += v & 0xFF; s1 += (v >> 8) & 0xFF; s2 += (v >> 16) & 0xFF; s3 += v >> 24;
        }
        int c = (r << 15) + 4 * ql;
        float d0 = s0 ? 1.0f / sqrtf((float)s0) : 0.0f;
        float d1 = s1 ? 1.0f / sqrtf((float)s1) : 0.0f;
        float d2 = s2 ? 1.0f / sqrtf((float)s2) : 0.0f;
        float d3 = s3 ? 1.0f / sqrtf((float)s3) : 0.0f;
        dinv[c] = d0; dinv[c + 1] = d1; dinv[c + 2] = d2; dinv[c + 3] = d3;
        sdeg[c]     = s0 ? sqrtf((float)s0) : 0.0f;
        sdeg[c + 1] = s1 ? sqrtf((float)s1) : 0.0f;
        sdeg[c + 2] = s2 ? sqrtf((float)s2) : 0.0f;
        sdeg[c + 3] = s3 ? sqrtf((float)s3) : 0.0f;
        ub0[c]     = __float2half(d0 * x[c]);
        ub0[c + 1] = __float2half(d1 * x[c + 1]);
        ub0[c + 2] = __float2half(d2 * x[c + 2]);
        ub0[c + 3] = __float2half(d3 * x[c + 3]);
    } else {
        __shared__ int tot[256];
        __shared__ int wsc[4];
        int b = tid;
        int run = 0;
        for (int s = 0; s < 128; ++s) {
            int c = bcnt[s * NBK + b];
            bcnt[s * NBK + b] = run;
            run += c;
        }
        tot[b] = run;
        __syncthreads();
        exscan256(b, tot, wsc);
        bbase[b] = tot[b];
        if (b == 0) bbase[256] = EE;
        for (int s = 0; s < 128; ++s)
            bcnt[s * NBK + b] += tot[b];
    }
}

// ---------------- coarse bucketing: LDS counting sort, coalesced flush ------
__global__ __launch_bounds__(1024) void k_bucket(const int* __restrict__ ei,
                                                 const int* __restrict__ boff,
                                                 unsigned* __restrict__ bkt) {
    __shared__ unsigned stage[BSL];
    __shared__ int cnt[NBK], cur[NBK], gbase[NBK];
    __shared__ int wsc[4];
    int s = blockIdx.x, tid = threadIdx.x;
    if (tid < NBK) cnt[tid] = 0;
    __syncthreads();
    const int* srcs = ei + s * BSL;
    const int* dsts = ei + EE + s * BSL;
    for (int i = tid; i < BSL; i += 1024)
        atomicAdd(&cnt[dsts[i] >> 8], 1);
    __syncthreads();
    if (tid < NBK) gbase[tid] = boff[s * NBK + tid];
    exscan256(tid, cnt, wsc);
    if (tid < NBK) cur[tid] = cnt[tid];
    __syncthreads();
    for (int i = tid; i < BSL; i += 1024) {
        int d = dsts[i];
        int pos = atomicAdd(&cur[d >> 8], 1);
        stage[pos] = (unsigned)srcs[i] | ((unsigned)d << 16);
    }
    __syncthreads();
    for (int j = tid; j < BSL; j += 1024) {
        unsigned rec = stage[j];
        int b = rec >> 24;
        bkt[gbase[b] + (j - cnt[b])] = rec;
    }
}

// -------- fine placement: exact CSR (rowp), src-only records; per-dst edge
//          lists ordered in 8 src-range runs (partitions 0-3 = src<32768) ---
__global__ __launch_bounds__(512) void k_place(const unsigned* __restrict__ bkt,
                                               const int* __restrict__ bbase,
                                               unsigned* __restrict__ ep,
                                               int* __restrict__ rowp) {
    __shared__ unsigned stage[STG];
    __shared__ int histP[NPART][NBK], curP[NPART][NBK];
    __shared__ int tot[NBK];
    __shared__ int wsc[4];
    int b = blockIdx.x, tid = threadIdx.x;
    int base = bbase[b], cnt = bbase[b + 1] - base;
    if (tid < NBK) {
#pragma unroll
        for (int p = 0; p < NPART; ++p) histP[p][tid] = 0;
    }
    __syncthreads();
    const unsigned* recs = bkt + base;
    for (int i = tid; i < cnt; i += 512) {
        unsigned rec = recs[i];
        atomicAdd(&histP[(rec & 0xFFFFu) >> 13][(rec >> 16) & 255], 1);
    }
    __syncthreads();
    if (tid < NBK) {
        int s = 0;
#pragma unroll
        for (int p = 0; p < NPART; ++p) s += histP[p][tid];
        tot[tid] = s;
    }
    __syncthreads();
    exscan256(tid, tot, wsc);                   // tot = exclusive start per dlow
    if (tid < NBK) {
        int st = tot[tid];
        rowp[b * NBK + tid] = base + st;
#pragma unroll
        for (int p = 0; p < NPART; ++p) {
            curP[p][tid] = st;
            st += histP[p][tid];
        }
    }
    if (b == 0 && tid == 0) rowp[NN] = EE;
    __syncthreads();
    for (int i = tid; i < cnt; i += 512) {
        unsigned rec = recs[i];
        int srcv = rec & 0xFFFF;
        int dlow = (rec >> 16) & 255;
        int pos = atomicAdd(&curP[srcv >> 13][dlow], 1);
        unsigned pk = (unsigned)srcv;
        if (pos < STG) stage[pos] = pk; else ep[base + pos] = pk;
    }
    __syncthreads();
    int lim = cnt < STG ? cnt : STG;
    for (int j = tid; j < lim; j += 512)
        ep[base + j] = stage[j];
}

// -------- degree-sort pass 1: per-block len8 histogram ---------------------
__global__ __launch_bounds__(1024) void k_dhist(const int* __restrict__ rowp,
                                                int* __restrict__ bh) {
    __shared__ int hist[DBIN];
    int blk = blockIdx.x, tid = threadIdx.x;
    if (tid < DBIN) hist[tid] = 0;
    __syncthreads();
    int n = blk * 1024 + tid;
    int deg = rowp[n + 1] - rowp[n];
    int pd = (deg + 7) & ~7;
    atomicAdd(&hist[pd >> 3], 1);
    __syncthreads();
    if (tid < DBIN) bh[blk * DBIN + tid] = hist[tid];
}

// -------- degree-sort pass 2: bin node-starts, bin edge-starts (closed-form
//          since all rows in bin have pd = 8*bin), per-block offsets --------
__global__ __launch_bounds__(256) void k_doff(const int* __restrict__ bh,
                                              int* __restrict__ off,
                                              int* __restrict__ nstart,
                                              int* __restrict__ estart) {
    __shared__ int tot[256];
    __shared__ int tote[256];
    __shared__ int wsc[4];
    int bin = threadIdx.x;
    int run = 0;
    for (int b = 0; b < 64; ++b) run += bh[b * DBIN + bin];
    tot[bin] = run;
    tote[bin] = run * (bin << 3);
    __syncthreads();
    exscan256(bin, tot, wsc);                    // node start per bin
    exscan256(bin, tote, wsc);                   // edge start per bin
    nstart[bin] = tot[bin];
    estart[bin] = tote[bin];
    int st = tot[bin];
    for (int b = 0; b < 64; ++b) {
        off[b * DBIN + bin] = st;
        st += bh[b * DBIN + bin];
    }
}

// -------- degree-sort pass 3: emit desc2 in sorted order with closed-form
//          padded edge offsets; rowp2[n] = sorted e0 -----------------------
__global__ __launch_bounds__(1024) void k_dscat(const int* __restrict__ rowp,
                                                const int* __restrict__ off,
                                                const int* __restrict__ nstart,
                                                const int* __restrict__ estart,
                                                uint4* __restrict__ desc2,
                                                int* __restrict__ rowp2) {
    __shared__ int loff[DBIN];
    int blk = blockIdx.x, tid = threadIdx.x;
    if (tid < DBIN) loff[tid] = off[blk * DBIN + tid];
    __syncthreads();
    int n = blk * 1024 + tid;
    int deg = rowp[n + 1] - rowp[n];
    int pd = (deg + 7) & ~7;
    int bin = pd >> 3;
    int pos = atomicAdd(&loff[bin], 1);
    int e0 = estart[bin] + (pos - nstart[bin]) * pd;
    desc2[pos] = make_uint4((unsigned)e0,
                            (unsigned)n | ((unsigned)bin << 16) |
                                ((unsigned)(pd - deg) << 24),
                            0u, 0u);
    rowp2[n] = e0;
}

// -------- emit padded ushort edge list AT SORTED OFFSETS (pads = 0xFFFF ->
//          row 65535, compensated by count) --------------------------------
__global__ __launch_bounds__(256) void k_copy(const int* __restrict__ rowp,
                                              const int* __restrict__ rowp2,
                                              const unsigned* __restrict__ ep,
                                              unsigned short* __restrict__ epp) {
    int idx = blockIdx.x * 256 + threadIdx.x;
    int n = idx >> 2, l = idx & 3;
    int a0 = rowp[n], a1 = rowp[n + 1], deg = a1 - a0;
    int b0 = rowp2[n];
    int pd = (deg + 7) & ~7;
    for (int i = l; i < deg; i += 4)
        epp[b0 + i] = (unsigned short)(ep[a0 + i] & 0xFFFFu);
    for (int i = deg + l; i < pd; i += 4) epp[b0 + i] = (unsigned short)0xFFFFu;
}

// ------- width-1 fp16 u-space propagation, single 128 KB LDS stage of the
//         full 64K-entry table:
//         u_out = -alpha * dinv[n]^2 * sum_src u_in[src]  - u_prev[n] -------
__global__ __launch_bounds__(1024) void k_prop1L(const uint4* __restrict__ desc,
                                                 const unsigned short* __restrict__ epp,
                                                 const __half* __restrict__ uin,
                                                 const __half* __restrict__ uprev,
                                                 const float* __restrict__ dinv,
                                                 __half* __restrict__ uout,
                                                 float alpha) {
    __shared__ _Float16 lds[65536];              // 128 KB, whole u table
    int tid = threadIdx.x;
    int q = blockIdx.x * 256 + (tid >> 2), l = tid & 3;
    uint4 d = desc[q];
    int e0 = (int)d.x;
    int n = d.y & 0xFFFF;
    int len8 = (d.y >> 16) & 0xFF;
    int pads = (int)(d.y >> 24);
    int e1 = e0 + (len8 << 3);
    {
        float4* l4 = (float4*)lds;
        const float4* u4 = (const float4*)uin;
        for (int i = tid; i < 8192; i += 1024) l4[i] = u4[i];
    }
    __syncthreads();
    float a = 0.f;
    for (int e = e0 + l; e < e1; e += 4) a += (float)lds[epp[e]];
    a += __shfl_xor(a, 1, 64);
    a += __shfl_xor(a, 2, 64);
    if (l == 0) {
        a -= (float)pads * (float)lds[65535];    // cancel pad contributions
        float dn = dinv[n];
        float u = -alpha * dn * dn * a;
        if (uprev) u -= __half2float(uprev[n]);
        uout[n] = __float2half(u);
    }
}

// ---- width-32 fp16 u-space propagation: weightless, padded uniform 8-edge
//      loop, 4 lanes/node (feature-column split), 16B gathers;
//      desc2 sorted by len8 AND epp relocated to match ---------------------
__global__ __launch_bounds__(256) void k_prop32(const uint4* __restrict__ desc,
                                                const unsigned short* __restrict__ epp,
                                                const __half* __restrict__ uin,
                                                const __half* __restrict__ uprev,
                                                const float* __restrict__ dinv,
                                                __half* __restrict__ uout,
                                                float alpha) {
    int idx = blockIdx.x * 256 + threadIdx.x;
    int q = idx >> 2, j8 = (idx & 3) << 3;
    uint4 d = desc[q];
    int e0 = (int)d.x;
    int n = d.y & 0xFFFF;
    int len8 = (d.y >> 16) & 0xFF;
    int pads = (int)(d.y >> 24);
    int e1 = e0 + (len8 << 3);
    const _Float16* tf = (const _Float16*)uin;
    float acc[8];
#pragma unroll
    for (int i = 0; i < 8; ++i) acc[i] = 0.f;
    for (int e = e0; e < e1; e += 8) {           // uniform: rows padded to x8
        uint4 pk = *(const uint4*)(epp + e);     // 8 ushort src indices
        unsigned s0 = pk.x & 0xFFFFu, s1 = pk.x >> 16;
        unsigned s2 = pk.y & 0xFFFFu, s3 = pk.y >> 16;
        unsigned s4 = pk.z & 0xFFFFu, s5 = pk.z >> 16;
        unsigned s6 = pk.w & 0xFFFFu, s7 = pk.w >> 16;
        half8 v0 = *(const half8*)(tf + (s0 << 5) + j8);
        half8 v1 = *(const half8*)(tf + (s1 << 5) + j8);
        half8 v2 = *(const half8*)(tf + (s2 << 5) + j8);
        half8 v3 = *(const half8*)(tf + (s3 << 5) + j8);
        half8 v4 = *(const half8*)(tf + (s4 << 5) + j8);
        half8 v5 = *(const half8*)(tf + (s5 << 5) + j8);
        half8 v6 = *(const half8*)(tf + (s6 << 5) + j8);
        half8 v7 = *(const half8*)(tf + (s7 << 5) + j8);
#pragma unroll
        for (int i = 0; i < 8; ++i)
            acc[i] += (float)v0[i] + (float)v1[i] + (float)v2[i] + (float)v3[i]
                    + (float)v4[i] + (float)v5[i] + (float)v6[i] + (float)v7[i];
    }
    if (pads) {                                  // cancel pad rows (u[65535])
        half8 z = *(const half8*)(tf + (0xFFFFu << 5) + j8);
        float pf = (float)pads;
#pragma unroll
        for (int i = 0; i < 8; ++i) acc[i] -= pf * (float)z[i];
    }
    float dn = dinv[n];
    float coef = -alpha * dn * dn;
    int o = (n << 5) + j8;
    half8 hu;
    if (uprev) {
        half8 pv = *(const half8*)((const _Float16*)uprev + o);
#pragma unroll
        for (int i = 0; i < 8; ++i) hu[i] = (_Float16)(coef * acc[i] - (float)pv[i]);
    } else {
#pragma unroll
        for (int i = 0; i < 8; ++i) hu[i] = (_Float16)(coef * acc[i]);
    }
    *(half8*)((_Float16*)uout + o) = hu;
}

// ---------------- layer-1 combine: h = relu(x*W0 + sd[n]*sum_k u_k*W[k] + b),
//                  emits only u0 = dinv*h for layer-2 props ----------------
__global__ __launch_bounds__(256) void k_comb1(const float* __restrict__ x,
                                               const __half* __restrict__ ub,
                                               const float* __restrict__ W,
                                               const float* __restrict__ b,
                                               const float* __restrict__ sdeg,
                                               const float* __restrict__ dinv,
                                               __half* __restrict__ uout) {
    int idx = blockIdx.x * 256 + threadIdx.x;
    int n = idx >> 5, j = idx & 31;
    float uacc = 0.f;
#pragma unroll
    for (int k = 1; k < KCH; ++k)
        uacc += __half2float(ub[k * NN + n]) * W[k * HID + j];
    float h = fmaxf(b[j] + x[n] * W[j] + sdeg[n] * uacc, 0.f);
    uout[idx] = __float2half(dinv[n] * h);
}

// ------- fused converts: Wl->fp16 padded-40 (blocks 0..2047), W2/W3 -> fp16
//         transposed (2048..2087), out bias init (2088) --------------------
__global__ __launch_bounds__(256) void k_cvtall(const float* __restrict__ Wl,
                                                __half* __restrict__ Wlh,
                                                const float* __restrict__ W2,
                                                const float* __restrict__ W3,
                                                _Float16* __restrict__ Wt2,
                                                _Float16* __restrict__ Wt3,
                                                const float* __restrict__ bl,
                                                float* __restrict__ out) {
    int blk = blockIdx.x, tid = threadIdx.x;
    if (blk < 2048) {
        __shared__ float s[128 * 33];
        const float* src = Wl + (size_t)blk * 128 * 33;
        for (int t = tid; t < 128 * 33; t += 256) s[t] = src[t];
        __syncthreads();
        unsigned* dst = (unsigned*)(Wlh + (size_t)blk * 128 * WLP);
        for (int t = tid; t < 128 * (WLP / 2); t += 256) {
            int row = t / (WLP / 2), c2 = t - row * (WLP / 2);
            int c0 = 2 * c2;
            float f0 = (c0 < 33) ? s[row * 33 + c0] : 0.f;
            float f1 = (c0 + 1 < 33) ? s[row * 33 + c0 + 1] : 0.f;
            __half2 h = __floats2half2_rn(f0, f1);
            dst[t] = *(unsigned*)&h;
        }
    } else if (blk < 2088) {
        int t = (blk - 2048) * 256 + tid;     // 0..10239
        const float* W = (t < 5120) ? W2 : W3;
        _Float16* Wt   = (t < 5120) ? Wt2 : Wt3;
        int tt = (t < 5120) ? t : t - 5120;
        if (tt < KCH * HID * HID) {
            int kc = tt >> 10, rem = tt & 1023, j = rem >> 5, i = rem & 31;
            Wt[tt] = (_Float16)W[kc * 1024 + i * 32 + j];
        }
    } else {
        if (tid < NG * OUTS) out[tid] = bl[tid % OUTS];
    }
}

// ---------------- MFMA combine on u-tables:
//   acc = sum_k u_k @ W[k];  v = sd[row]*acc + b;  (relu)
//   hout (if set) = v;  uout (if set) = dinv[row]*v ------------------------
__global__ __launch_bounds__(256) void k_comb32(const __half* tx,
                                                const _Float16* __restrict__ Wt,
                                                const float* __restrict__ b,
                                                const float* __restrict__ sdeg,
                                                const float* __restrict__ dinv,
                                                __half* hout,
                                                __half* uout,
                                                int relu) {
    int tid = threadIdx.x;
    int lane = tid & 63;
    int wave = (blockIdx.x * 256 + tid) >> 6;   // 0..1023
    int m = lane & 15, kg = lane >> 4;
    half8 Bf[KCH][2];
#pragma unroll
    for (int kc = 0; kc < KCH; ++kc)
#pragma unroll
        for (int h = 0; h < 2; ++h)
            Bf[kc][h] = *(const half8*)(Wt + kc * 1024 + (h * 16 + m) * 32 + kg * 8);
    float bj0 = b[m], bj1 = b[16 + m];
    const size_t S = (size_t)NN * HID;
    const _Float16* txf = (const _Float16*)tx;
#pragma unroll
    for (int t = 0; t < 4; ++t) {
        int nb = (wave * 4 + t) << 4;
        floatx4 acc0 = {0.f, 0.f, 0.f, 0.f}, acc1 = {0.f, 0.f, 0.f, 0.f};
#pragma unroll
        for (int kc = 0; kc < KCH; ++kc) {
            half8 Af = *(const half8*)(txf + (size_t)kc * S + (size_t)(nb + m) * 32 + kg * 8);
            acc0 = __builtin_amdgcn_mfma_f32_16x16x32_f16(Af, Bf[kc][0], acc0, 0, 0, 0);
            acc1 = __builtin_amdgcn_mfma_f32_16x16x32_f16(Af, Bf[kc][1], acc1, 0, 0, 0);
        }
        int rowb = nb + kg * 4;
#pragma unroll
        for (int r = 0; r < 4; ++r) {
            int row = rowb + r;
            float sd = sdeg[row];
            float v0 = sd * acc0[r] + bj0, v1 = sd * acc1[r] + bj1;
            if (relu) { v0 = fmaxf(v0, 0.f); v1 = fmaxf(v1, 0.f); }
            if (hout) {
                hout[(size_t)row * 32 + m]      = __float2half(v0);
                hout[(size_t)row * 32 + 16 + m] = __float2half(v1);
            }
            if (uout) {
                float dn = dinv[row];
                uout[(size_t)row * 32 + m]      = __float2half(dn * v0);
                uout[(size_t)row * 32 + 16 + m] = __float2half(dn * v1);
            }
        }
    }
}

// ---------------- readout: 5x dwordx4 Wl rows ----------------
__global__ __launch_bounds__(256) void k_readout(const __half* __restrict__ h,
                                                 const __half* __restrict__ Wlh,
                                                 float* __restrict__ out) {
    int gp = blockIdx.x >> 7;
    int mc = blockIdx.x & 127;
    int tid = threadIdx.x;
    int g0 = gp * 2, g1 = g0 + 1;
    float acc0[OUTS], acc1[OUTS];
#pragma unroll
    for (int o = 0; o < OUTS; ++o) { acc0[o] = 0.f; acc1[o] = 0.f; }
    const __half* h0 = h + (size_t)g0 * GSZ;
    const __half* h1 = h + (size_t)g1 * GSZ;
    for (int it = 0; it < 8; ++it) {
        int m = mc * 2048 + it * 256 + tid;
        float hv0 = __half2float(h0[m]);
        float hv1 = __half2float(h1[m]);
        const uint4* rp = (const uint4*)(Wlh + (size_t)m * WLP);   // 80B rows, 16B aligned
        uint4 q0 = rp[0], q1 = rp[1], q2 = rp[2], q3 = rp[3], q4 = rp[4];
        unsigned u[17] = {q0.x, q0.y, q0.z, q0.w, q1.x, q1.y, q1.z, q1.w,
                          q2.x, q2.y, q2.z, q2.w, q3.x, q3.y, q3.z, q3.w, q4.x};
#pragma unroll
        for (int q = 0; q < 16; ++q) {
            float2 f = __half22float2(*(__half2*)&u[q]);
            acc0[2 * q]     += hv0 * f.x;  acc1[2 * q]     += hv1 * f.x;
            acc0[2 * q + 1] += hv0 * f.y;  acc1[2 * q + 1] += hv1 * f.y;
        }
        float lw = __half2float(__low2half(*(__half2*)&u[16]));
        acc0[32] += hv0 * lw;  acc1[32] += hv1 * lw;
    }
    __shared__ float red[4][2 * OUTS];
    int lane = tid & 63, w = tid >> 6;
#pragma unroll
    for (int o = 0; o < OUTS; ++o) {
        float v0 = acc0[o], v1 = acc1[o];
        for (int off = 32; off > 0; off >>= 1) {
            v0 += __shfl_down(v0, off, 64);
            v1 += __shfl_down(v1, off, 64);
        }
        if (lane == 0) { red[w][o] = v0; red[w][OUTS + o] = v1; }
    }
    __syncthreads();
    if (tid < 2 * OUTS) {
        float s = red[0][tid] + red[1][tid] + red[2][tid] + red[3][tid];
        int g = (tid < OUTS) ? g0 : g1;
        int o = (tid < OUTS) ? tid : tid - OUTS;
        atomicAdd(&out[g * OUTS + o], s);
    }
}

extern "C" void kernel_launch(void* const* d_in, const int* in_sizes, int n_in,
                              void* d_out, int out_size, void* d_ws, size_t ws_size,
                              hipStream_t stream) {
    const float* x  = (const float*)d_in[0];
    const int*   ei = (const int*)d_in[1];
    const float* W1 = (const float*)d_in[3];
    const float* b1 = (const float*)d_in[4];
    const float* W2 = (const float*)d_in[5];
    const float* b2 = (const float*)d_in[6];
    const float* W3 = (const float*)d_in[7];
    const float* b3 = (const float*)d_in[8];
    const float* Wl = (const float*)d_in[9];
    const float* bl = (const float*)d_in[10];
    float* out = (float*)d_out;

    char* ws = (char*)d_ws;
    size_t off = 0;
    auto alloc = [&](size_t bytes) -> void* {
        void* p = ws + off;
        off += (bytes + 255) & ~(size_t)255;
        return p;
    };
    unsigned char* pdeg = (unsigned char*)alloc((size_t)2 * SLICES * RSIZE);
    int*      bcnt   = (int*)alloc((size_t)128 * NBK * 4);
    int*      bbase  = (int*)alloc((size_t)257 * 4);
    int*      rowp   = (int*)alloc((size_t)(NN + 1) * 4);
    int*      rowp2  = (int*)alloc((size_t)NN * 4);
    int*      bh     = (int*)alloc((size_t)64 * DBIN * 4);
    int*      boffs  = (int*)alloc((size_t)64 * DBIN * 4);
    int*      nstart = (int*)alloc((size_t)DBIN * 4);
    int*      estart = (int*)alloc((size_t)DBIN * 4);
    float*    dinv   = (float*)alloc((size_t)NN * 4);
    float*    sdeg   = (float*)alloc((size_t)NN * 4);
    unsigned* bkt    = (unsigned*)alloc((size_t)EE * 4);
    unsigned* ep     = (unsigned*)alloc((size_t)EE * 4);
    unsigned short* epp = (unsigned short*)alloc((size_t)EPCAP * 2);
    uint4*    desc2  = (uint4*)alloc((size_t)NN * 16);
    __half*   ub     = (__half*)alloc((size_t)5 * NN * 2);          // u0..u4 (layer 1, fp16)
    __half*   utx    = (__half*)alloc((size_t)KCH * NN * HID * 2);  // u0..u4 (layers 2/3)
    __half*   hfin   = (__half*)alloc((size_t)NN * HID * 2);
    __half*   Wlh    = (__half*)alloc((size_t)GSZ * WLP * 2);
    _Float16* Wt2    = (_Float16*)alloc((size_t)KCH * HID * HID * 2);
    _Float16* Wt3    = (_Float16*)alloc((size_t)KCH * HID * HID * 2);

    // ---- CSR build (atomic-free) + degree-sorted padded edge list ----
    k_hist2<<<256, 1024, 0, stream>>>(ei, pdeg, bcnt);
    k_hredscan<<<65, 256, 0, stream>>>(pdeg, dinv, sdeg, bcnt, bbase, x, ub);
    k_bucket<<<128, 1024, 0, stream>>>(ei, bcnt, bkt);
    k_place<<<256, 512, 0, stream>>>(bkt, bbase, ep, rowp);
    k_dhist<<<64, 1024, 0, stream>>>(rowp, bh);
    k_doff<<<1, 256, 0, stream>>>(bh, boffs, nstart, estart);
    k_dscat<<<64, 1024, 0, stream>>>(rowp, boffs, nstart, estart, desc2, rowp2);
    k_copy<<<1024, 256, 0, stream>>>(rowp, rowp2, ep, epp);
    k_cvtall<<<2089, 256, 0, stream>>>(Wl, Wlh, W2, W3, Wt2, Wt3, bl, out);

    // ---- layer 1 (width-1, fp16 tables, single 128 KB LDS stage) ----
    k_prop1L<<<256, 1024, 0, stream>>>(desc2, epp, ub,          nullptr,     dinv, ub + NN,     1.f);
    k_prop1L<<<256, 1024, 0, stream>>>(desc2, epp, ub + NN,     ub,          dinv, ub + 2 * NN, 2.f);
    k_prop1L<<<256, 1024, 0, stream>>>(desc2, epp, ub + 2 * NN, ub + NN,     dinv, ub + 3 * NN, 2.f);
    k_prop1L<<<256, 1024, 0, stream>>>(desc2, epp, ub + 3 * NN, ub + 2 * NN, dinv, ub + 4 * NN, 2.f);
    k_comb1<<<(NN * HID) / 256, 256, 0, stream>>>(x, ub, W1, b1, sdeg, dinv, utx);

    const size_t S = (size_t)NN * HID;
    const int PG = (NN * 4) / 256;    // 1024 blocks, 4 lanes/node
    // ---- layer 2 (u-space) ----
    k_prop32<<<PG, 256, 0, stream>>>(desc2, epp, utx,         nullptr,      dinv, utx + 1 * S, 1.f);
    k_prop32<<<PG, 256, 0, stream>>>(desc2, epp, utx + 1 * S, utx,          dinv, utx + 2 * S, 2.f);
    k_prop32<<<PG, 256, 0, stream>>>(desc2, epp, utx + 2 * S, utx + 1 * S,  dinv, utx + 3 * S, 2.f);
    k_prop32<<<PG, 256, 0, stream>>>(desc2, epp, utx + 3 * S, utx + 2 * S,  dinv, utx + 4 * S, 2.f);
    k_comb32<<<256, 256, 0, stream>>>(utx, Wt2, b2, sdeg, dinv, nullptr, utx, 1);  // u0' in place

    // ---- layer 3 (u-space, no relu, emit h only) ----
    k_prop32<<<PG, 256, 0, stream>>>(desc2, epp, utx,         nullptr,      dinv, utx + 1 * S, 1.f);
    k_prop32<<<PG, 256, 0, stream>>>(desc2, epp, utx + 1 * S, utx,          dinv, utx + 2 * S, 2.f);
    k_prop32<<<PG, 256, 0, stream>>>(desc2, epp, utx + 2 * S, utx + 1 * S,  dinv, utx + 3 * S, 2.f);
    k_prop32<<<PG, 256, 0, stream>>>(desc2, epp, utx + 3 * S, utx + 2 * S,  dinv, utx + 4 * S, 2.f);
    k_comb32<<<256, 256, 0, stream>>>(utx, Wt3, b3, sdeg, nullptr, hfin, nullptr, 0);

    // ---- readout ----
    k_readout<<<512, 256, 0, stream>>>(hfin, Wlh, out);
}